// Round 6
// baseline (2526.793 us; speedup 1.0000x reference)
//
#include <hip/hip_runtime.h>
#include <float.h>
#include <math.h>

// ============================================================================
// BeamSearchDecoder — MI355X. Greedy-equivalence: h0 = repeat(enc_h,K) and
// scores0 = 0 make all K=3 beams identical; the 9 candidates per batch are
// [v0,v1,v2]x3 and top-3 = three copies of v0 regardless of tie-break, so
// every beam takes the argmax token forever. decoded = one-hot(greedy seq),
// h = final greedy h x3, scores = cumulative (max - logsumexp) x3.
//
// All logits math fp32 (argmax decisions must track the fp32 numpy ref).
//
// R6 vs R5 (2144 us): gemv was LDS-issue-bound (1024 ds_read_b128/thread at
// ~12 cyc fixed cost = ~41 us/step). h is wave-uniform -> feed it through the
// SCALAR pipe: k_gru co-writes hT[k][r]; gemv inline-asm s_load_dwordx8 pulls
// 8 rows x 4 k into SGPRs per group; v_fma uses the SGPR operand directly.
// No LDS, no h-VMEM. W_out read in NATIVE layout (transpose kernel deleted),
// bias+max/argmax/sumexp fused into gemv (combine kernel + lpart deleted).
// Grid 500 blocks (125 vocab-chunks x 4 row-groups of 8) = 2 waves/SIMD.
// ============================================================================

#define BB 32
#define HH 512
#define EE 256
#define VV 32000
#define TSTEPS 32
#define NVCH 125                             // vocab chunks of 256 cols
#define PSTR 128                             // pm/ps/pidx row stride
#define DEC_ELEMS (BB * (TSTEPS + 1) * VV)   // 33,792,000
#define H_ELEMS (BB * 3 * HH)                // 49,152

typedef __attribute__((ext_vector_type(8))) float f32x8;

// ---------------------------------------------------------------------------
// Setup: h0 = encoder_hidden, scores = 0, seq col 0 = START(=1)
// ---------------------------------------------------------------------------
__global__ __launch_bounds__(256) void k_init(
    const float* __restrict__ enc_h, float* __restrict__ hb0,
    float* __restrict__ scores, int* __restrict__ tok_seq) {
  int idx = blockIdx.x * 256 + threadIdx.x;  // 64*256
  if (idx < BB * HH) hb0[idx] = enc_h[idx];
  if (idx < BB) { scores[idx] = 0.0f; tok_seq[idx] = 1; }
}

// ---------------------------------------------------------------------------
// Fused logits GEMV + bias + per-(row, 256-col chunk) max/argmax/sumexp.
// Grid 500 = (vb 0..124 of 256 cols) x (rg 0..3 of 8 rows). Block 256 thr.
// Thread: one vocab col v = vb*256+tid, 8 row accumulators, full K=512.
// h feed: s_load_dwordx8 (8 rows, one k) x4 per group from hT[k][r] — pure
// scalar-pipe broadcast; FMAs consume SGPRs directly. w feed: native-layout
// W_out[v*512+k] float4 loads, double-buffered per 16-k group.
// ---------------------------------------------------------------------------
__global__ __launch_bounds__(256) void k_gemv(
    const float* __restrict__ W,     // (V, H) native W_out
    const float* __restrict__ bout,  // (V)
    const float* __restrict__ hT,    // (H, 32): hT[k*32 + r]
    float* __restrict__ pm, float* __restrict__ ps, int* __restrict__ pidx) {
  const int tid = threadIdx.x;
  const int vb = blockIdx.x >> 2;        // 0..124
  const int r0 = (blockIdx.x & 3) * 8;   // 0,8,16,24
  const int v = vb * 256 + tid;          // < 32000 exact

  float acc[8];
#pragma unroll
  for (int r = 0; r < 8; ++r) acc[r] = 0.0f;

  const float* wp = W + (size_t)v * HH;
  const float* hp = hT + r0;

  float4 wb[4];
#pragma unroll
  for (int i = 0; i < 4; ++i) wb[i] = *(const float4*)(wp + i * 4);

  for (int kg = 0; kg < HH; kg += 16) {
    float4 wn[4];
    const int kn = kg + 16;
    if (kn < HH) {
#pragma unroll
      for (int i = 0; i < 4; ++i) wn[i] = *(const float4*)(wp + kn + i * 4);
    } else {
#pragma unroll
      for (int i = 0; i < 4; ++i) wn[i] = wb[i];
    }
#pragma unroll
    for (int sub = 0; sub < 4; ++sub) {
      f32x8 h0, h1, h2, h3;  // rows r0..r0+7 at k, k+1, k+2, k+3
      asm volatile(
          "s_load_dwordx8 %0, %4, 0x0\n\t"
          "s_load_dwordx8 %1, %4, 0x80\n\t"
          "s_load_dwordx8 %2, %4, 0x100\n\t"
          "s_load_dwordx8 %3, %4, 0x180\n\t"
          "s_waitcnt lgkmcnt(0)"
          : "=s"(h0), "=s"(h1), "=s"(h2), "=s"(h3)
          : "s"(hp));
      const float4 w4 = wb[sub];
#pragma unroll
      for (int r = 0; r < 8; ++r) {
        acc[r] = fmaf(h0[r], w4.x, acc[r]);
        acc[r] = fmaf(h1[r], w4.y, acc[r]);
        acc[r] = fmaf(h2[r], w4.z, acc[r]);
        acc[r] = fmaf(h3[r], w4.w, acc[r]);
      }
      hp += 128;  // 4 k's * 32 floats
    }
#pragma unroll
    for (int i = 0; i < 4; ++i) wb[i] = wn[i];
  }

  // ---- fused epilogue: l = acc + bias; per-row chunk max/argmax/sumexp ----
  const float bv = bout[v];
  float l[8], tm[8]; int ti_[8];
#pragma unroll
  for (int r = 0; r < 8; ++r) { l[r] = acc[r] + bv; tm[r] = l[r]; ti_[r] = v; }
#pragma unroll
  for (int off = 1; off < 64; off <<= 1) {
#pragma unroll
    for (int r = 0; r < 8; ++r) {
      const float om = __shfl_xor(tm[r], off);
      const int oi = __shfl_xor(ti_[r], off);
      if (om > tm[r] || (om == tm[r] && oi < ti_[r])) { tm[r] = om; ti_[r] = oi; }
    }
  }
  __shared__ float wm[4][8]; __shared__ int wi2[4][8];
  __shared__ float bm[8]; __shared__ int bi[8];
  __shared__ float wsum[4][8];
  const int wv = tid >> 6, lane = tid & 63;
  if (lane == 0) {
#pragma unroll
    for (int r = 0; r < 8; ++r) { wm[wv][r] = tm[r]; wi2[wv][r] = ti_[r]; }
  }
  __syncthreads();
  if (tid < 8) {
    float m = wm[0][tid]; int ii = wi2[0][tid];
#pragma unroll
    for (int w = 1; w < 4; ++w) {
      if (wm[w][tid] > m || (wm[w][tid] == m && wi2[w][tid] < ii)) {
        m = wm[w][tid]; ii = wi2[w][tid];
      }
    }
    bm[tid] = m; bi[tid] = ii;
  }
  __syncthreads();
  float sv[8];
#pragma unroll
  for (int r = 0; r < 8; ++r) sv[r] = __expf(l[r] - bm[r]);
#pragma unroll
  for (int off = 1; off < 64; off <<= 1) {
#pragma unroll
    for (int r = 0; r < 8; ++r) sv[r] += __shfl_xor(sv[r], off);
  }
  if (lane == 0) {
#pragma unroll
    for (int r = 0; r < 8; ++r) wsum[wv][r] = sv[r];
  }
  __syncthreads();
  if (tid < 8) {
    const int row = r0 + tid;
    pm[row * PSTR + vb] = bm[tid];
    ps[row * PSTR + vb] = wsum[0][tid] + wsum[1][tid] + wsum[2][tid] + wsum[3][tid];
    pidx[row * PSTR + vb] = bi[tid];
  }
}

// ---------------------------------------------------------------------------
// GRU step with fused token-select prologue. Grid 128 = (rg 0..7 of 4 rows) x
// (jt 0..15 of 32 H-cols). Block 256 thr. Native-layout W reads.
// Also co-writes hT[j][r] for the gemv scalar feed. step==TSTEPS: select only.
// ---------------------------------------------------------------------------
__global__ __launch_bounds__(256) void k_gru(
    const int step,
    const float* __restrict__ emb,
    const float* __restrict__ W_ih,   // (1536, 256) native
    const float* __restrict__ W_hh,   // (1536, 512) native
    const float* __restrict__ b_ih, const float* __restrict__ b_hh,
    const float* __restrict__ hin, float* __restrict__ hout,
    float* __restrict__ hT,
    const float* __restrict__ pm, const float* __restrict__ ps,
    const int* __restrict__ pidx,
    float* __restrict__ scores, int* __restrict__ tok_seq) {
  const int tid = threadIdx.x;
  const int rg = blockIdx.x >> 4;   // 0..7
  const int jt = blockIdx.x & 15;   // 0..15
  const int r0 = rg * 4, j0 = jt * 32;
  const int lane = tid & 63, wv = tid >> 6;  // wv 0..3

  __shared__ int toks[4];
  __shared__ float xs[4][EE];
  __shared__ float hsm[4][HH];
  __shared__ float gpart[24 * 272];

  // ---- select: reduce 125 chunk-partials for row r0+wv ----
  if (step == 0) {
    if (tid < 4) toks[tid] = 1;  // START
  } else {
    const int row = r0 + wv;
    const float* pmr = pm + row * PSTR;
    const float* psr = ps + row * PSTR;
    const int* pir = pidx + row * PSTR;
    const float m1 = pmr[lane];          // lane < 64 <= 125: always valid
    const float s1 = psr[lane];
    const int i1 = pir[lane];
    const bool cv2 = (lane + 64 < NVCH);
    const float m2 = cv2 ? pmr[lane + 64] : -FLT_MAX;
    const float s2 = cv2 ? psr[lane + 64] : 0.0f;
    const int i2 = cv2 ? pir[lane + 64] : 0x7fffffff;
    float gm; int gi;
    if (m2 > m1 || (m2 == m1 && i2 < i1)) { gm = m2; gi = i2; }
    else { gm = m1; gi = i1; }
#pragma unroll
    for (int off = 1; off < 64; off <<= 1) {
      const float om = __shfl_xor(gm, off);
      const int oi = __shfl_xor(gi, off);
      if (om > gm || (om == gm && oi < gi)) { gm = om; gi = oi; }
    }
    float term = s1 * __expf(m1 - gm) + (cv2 ? s2 * __expf(m2 - gm) : 0.0f);
#pragma unroll
    for (int off = 1; off < 64; off <<= 1) term += __shfl_xor(term, off);
    if (lane == 0) {
      toks[wv] = gi;
      if (jt == 0) {
        scores[row] -= logf(term);      // += max - logsumexp
        tok_seq[step * BB + row] = gi;  // seq column `step`
      }
    }
  }
  __syncthreads();
  if (step == TSTEPS) return;

  // ---- stage x = relu(emb[tok]) and h_prev ----
  for (int i = tid; i < 4 * EE; i += 256) {
    const int r = i >> 8, c = i & (EE - 1);
    const float e = emb[(size_t)toks[r] * EE + c];
    xs[r][c] = e > 0.0f ? e : 0.0f;
  }
  for (int i = tid; i < 4 * HH; i += 256) {
    const int r = i >> 9, c = i & (HH - 1);
    hsm[r][c] = hin[(r0 + r) * HH + c];
  }
  __syncthreads();

  const int jh = tid & 31, kq = tid >> 5;  // 32 cols x 8 k-slices
  const int j = j0 + jh;
  float ai[3][4], ah[3][4];
#pragma unroll
  for (int g = 0; g < 3; ++g)
#pragma unroll
    for (int r = 0; r < 4; ++r) { ai[g][r] = 0.0f; ah[g][r] = 0.0f; }

#pragma unroll 2
  for (int q = 0; q < 8; ++q) {
    const int k4 = kq * 32 + q * 4;
    float4 xr[4];
#pragma unroll
    for (int r = 0; r < 4; ++r) xr[r] = *(const float4*)&xs[r][k4];
#pragma unroll
    for (int g = 0; g < 3; ++g) {
      const float4 w = *(const float4*)&W_ih[(size_t)(g * HH + j) * EE + k4];
#pragma unroll
      for (int r = 0; r < 4; ++r) {
        ai[g][r] = fmaf(xr[r].x, w.x, ai[g][r]);
        ai[g][r] = fmaf(xr[r].y, w.y, ai[g][r]);
        ai[g][r] = fmaf(xr[r].z, w.z, ai[g][r]);
        ai[g][r] = fmaf(xr[r].w, w.w, ai[g][r]);
      }
    }
  }
#pragma unroll 2
  for (int q = 0; q < 16; ++q) {
    const int k4 = kq * 64 + q * 4;
    float4 hr[4];
#pragma unroll
    for (int r = 0; r < 4; ++r) hr[r] = *(const float4*)&hsm[r][k4];
#pragma unroll
    for (int g = 0; g < 3; ++g) {
      const float4 w = *(const float4*)&W_hh[(size_t)(g * HH + j) * HH + k4];
#pragma unroll
      for (int r = 0; r < 4; ++r) {
        ah[g][r] = fmaf(hr[r].x, w.x, ah[g][r]);
        ah[g][r] = fmaf(hr[r].y, w.y, ah[g][r]);
        ah[g][r] = fmaf(hr[r].z, w.z, ah[g][r]);
        ah[g][r] = fmaf(hr[r].w, w.w, ah[g][r]);
      }
    }
  }
  {
    const int base = kq * 34 + jh;
#pragma unroll
    for (int g = 0; g < 3; ++g)
#pragma unroll
      for (int r = 0; r < 4; ++r) {
        gpart[(g * 4 + r) * 272 + base] = ai[g][r];
        gpart[(12 + g * 4 + r) * 272 + base] = ah[g][r];
      }
  }
  __syncthreads();

  if (tid < 128) {
    const int r = tid >> 5, jh2 = tid & 31;
    const int j2 = j0 + jh2;
    float g6[6];
#pragma unroll
    for (int c = 0; c < 6; ++c) {
      const int cc = (c < 3) ? (c * 4 + r) : (12 + (c - 3) * 4 + r);
      float s = 0.0f;
#pragma unroll
      for (int q = 0; q < 8; ++q) s += gpart[cc * 272 + q * 34 + jh2];
      g6[c] = s;
    }
    const float ir = g6[0] + b_ih[j2];
    const float iz = g6[1] + b_ih[HH + j2];
    const float in_ = g6[2] + b_ih[2 * HH + j2];
    const float hr_ = g6[3] + b_hh[j2];
    const float hz = g6[4] + b_hh[HH + j2];
    const float hn = g6[5] + b_hh[2 * HH + j2];
    const float rr = 1.0f / (1.0f + expf(-(ir + hr_)));
    const float zz = 1.0f / (1.0f + expf(-(iz + hz)));
    const float nn = tanhf(in_ + rr * hn);
    const float val = (1.0f - zz) * nn + zz * hsm[r][j2];
    hout[(r0 + r) * HH + j2] = val;
    hT[j2 * 32 + (r0 + r)] = val;   // transposed copy for gemv scalar feed
  }
}

// ---------------------------------------------------------------------------
// Full-output writer: one-hot rows composed inline (no memset), h x3,
// scores x3. All stores float4, coalesced.
// ---------------------------------------------------------------------------
__global__ __launch_bounds__(256) void k_out(
    const int* __restrict__ tok_seq, const float* __restrict__ hfin,
    const float* __restrict__ scores, float* __restrict__ out) {
  const int blk = blockIdx.x, tid = threadIdx.x;
  if (blk < BB * (TSTEPS + 1)) {           // one (b,t) one-hot row
    const int b = blk / (TSTEPS + 1), t = blk % (TSTEPS + 1);
    const int tok = tok_seq[t * BB + b];
    const int tq = tok >> 2, tl = tok & 3;
    float4* op = (float4*)(out + (size_t)blk * VV);
    for (int i = tid; i < VV / 4; i += 256) {
      float4 z = {0.0f, 0.0f, 0.0f, 0.0f};
      if (i == tq) (&z.x)[tl] = 1.0f;
      op[i] = z;
    }
  } else if (blk < BB * (TSTEPS + 1) + 12) {  // h x3: 12288 float4
#pragma unroll
    for (int it = 0; it < 4; ++it) {
      const int idx = (blk - BB * (TSTEPS + 1)) * 1024 + it * 256 + tid;
      if (idx < H_ELEMS / 4) {
        const int fi = idx * 4;
        const int b = fi / (3 * HH);
        const int j0 = (fi % (3 * HH)) % HH;
        ((float4*)(out + DEC_ELEMS))[idx] =
            *(const float4*)(hfin + b * HH + j0);
      }
    }
  } else {                                   // scores x3: 96 floats
    if (tid < BB * 3) {
      out[(size_t)DEC_ELEMS + H_ELEMS + tid] = scores[tid / 3];
    }
  }
}

// ---------------------------------------------------------------------------
extern "C" void kernel_launch(void* const* d_in, const int* in_sizes, int n_in,
                              void* d_out, int out_size, void* d_ws, size_t ws_size,
                              hipStream_t stream) {
  const float* enc_h = (const float*)d_in[1];
  const float* emb   = (const float*)d_in[2];
  const float* W_ih  = (const float*)d_in[3];
  const float* W_hh  = (const float*)d_in[4];
  const float* b_ih  = (const float*)d_in[5];
  const float* b_hh  = (const float*)d_in[6];
  const float* W_out = (const float*)d_in[7];
  const float* b_out = (const float*)d_in[8];
  float* out = (float*)d_out;

  // workspace layout (floats) — ~100 KB total
  float* ws = (float*)d_ws;
  float* hb0     = ws;                       // 16,384
  float* hb1     = hb0 + BB * HH;            // 16,384
  float* hT      = hb1 + BB * HH;            // 16,384 (512 x 32)
  float* pm      = hT + HH * BB;             // 32*128
  float* ps      = pm + BB * PSTR;           // 32*128
  float* scores  = ps + BB * PSTR;           // 32
  int*   pidx    = (int*)(scores + BB);      // 32*128
  int*   tok_seq = pidx + BB * PSTR;         // 33*32

  k_init<<<64, 256, 0, stream>>>(enc_h, hb0, scores, tok_seq);

  for (int t = 0; t < TSTEPS; ++t) {
    float* hin  = (t & 1) ? hb1 : hb0;
    float* hout = (t & 1) ? hb0 : hb1;
    k_gru<<<128, 256, 0, stream>>>(t, emb, W_ih, W_hh, b_ih, b_hh,
                                   hin, hout, hT, pm, ps, pidx, scores, tok_seq);
    k_gemv<<<500, 256, 0, stream>>>(W_out, b_out, hT, pm, ps, pidx);
  }
  // final selection: seq col 32 + last score term
  k_gru<<<128, 256, 0, stream>>>(TSTEPS, emb, W_ih, W_hh, b_ih, b_hh,
                                 hb0, hb1, hT, pm, ps, pidx, scores, tok_seq);
  // final h lives in hb0 (t=31 odd: hout=hb0); full-output writer
  k_out<<<BB * (TSTEPS + 1) + 13, 256, 0, stream>>>(tok_seq, hb0, scores, out);
}

// Round 7
// 1941.500 us; speedup vs baseline: 1.3015x; 1.3015x over previous
//
#include <hip/hip_runtime.h>
#include <float.h>
#include <math.h>

// ============================================================================
// BeamSearchDecoder — MI355X. Greedy-equivalence: h0 = repeat(enc_h,K) and
// scores0 = 0 make all K=3 beams identical; the 9 candidates per batch are
// [v0,v1,v2]x3 and top-3 = three copies of v0 regardless of tie-break, so
// every beam takes the argmax token forever. decoded = one-hot(greedy seq),
// h = final greedy h x3, scores = cumulative (max - logsumexp) x3.
//
// All logits math fp32 (argmax decisions must track the fp32 numpy ref).
//
// R7 vs R6 (2527, REGRESSION): R6's native-W layout was uncoalesced
// (64 cache lines per wave-load) and 4x re-read; scalar h-feed serialized on
// lgkmcnt(0). Revert to R5 skeleton (transposed Wt read ONCE, LDS h) and fix
// R5's DS-bound inner loop: NV=2 cols/thread -> 1 ds_read_b128 per 8 FMAs
// (DS 6.1k cyc vs FMA 8.2k cyc per thread, overlappable). Grid (63,8) = 504
// blocks = 2 waves/SIMD. Split-K=8 partials + combine kernel (ws-adaptive).
// ============================================================================

#define BB 32
#define HH 512
#define EE 256
#define VV 32000
#define TSTEPS 32
#define NVCH 63                              // 512-col chunks (last = 256)
#define PSTR 64                              // pm/ps/pidx row stride
#define DEC_ELEMS (BB * (TSTEPS + 1) * VV)   // 33,792,000
#define H_ELEMS (BB * 3 * HH)                // 49,152

// ---------------------------------------------------------------------------
// Setup: tiled transpose W_out (V,H) -> Wt_out (H,V)
// ---------------------------------------------------------------------------
__global__ __launch_bounds__(256) void k_transpose_out(
    const float* __restrict__ W, float* __restrict__ Wt) {
  __shared__ float t[32][33];
  const int vb = blockIdx.x * 32;  // 1000
  const int kb = blockIdx.y * 32;  // 16
  const int c = threadIdx.x & 31, rq = threadIdx.x >> 5;
#pragma unroll
  for (int i = 0; i < 4; ++i) {
    int r = rq + i * 8;
    t[r][c] = W[(size_t)(vb + r) * HH + kb + c];
  }
  __syncthreads();
#pragma unroll
  for (int i = 0; i < 4; ++i) {
    int r = rq + i * 8;
    Wt[(size_t)(kb + r) * VV + vb + c] = t[c][r];
  }
}

// ---------------------------------------------------------------------------
// Setup: h0 = encoder_hidden, scores = 0, seq col 0 = START(=1)
// ---------------------------------------------------------------------------
__global__ __launch_bounds__(256) void k_init(
    const float* __restrict__ enc_h, float* __restrict__ hb0,
    float* __restrict__ scores, int* __restrict__ tok_seq) {
  int idx = blockIdx.x * 256 + threadIdx.x;  // 64*256
  if (idx < BB * HH) hb0[idx] = enc_h[idx];
  if (idx < BB) { scores[idx] = 0.0f; tok_seq[idx] = 1; }
}

// ---------------------------------------------------------------------------
// Split-K logits GEMV. Grid (63 vb, nkc kc). Block 256 thr.
// Thread: cols v0 = vb*512+tid, v1 = v0+256; 32 row-accumulators EACH
// (64 total) over KLEN k's. h chunk in LDS, read as wave-uniform b128
// broadcast — 1 DS per 8 FMAs. W (transposed) read once across the grid,
// double-buffered per 4-k group. Writes fp32 partials lpart[kc][row][v].
// ---------------------------------------------------------------------------
template <int KLEN>
__global__ __launch_bounds__(256) void k_gemv(
    const float* __restrict__ Wt,    // (H, V)
    const float* __restrict__ hmat,  // (B, H)
    float* __restrict__ lpart) {     // (nkc, B, V)
  __shared__ float hs[32 * KLEN];
  const int tid = threadIdx.x;
  const int vb = blockIdx.x;         // 0..62
  const int kc = blockIdx.y;
  const int k0 = kc * KLEN;

  // stage h chunk: hs[r][k'] = hmat[r*HH + k0 + k']
  {
    constexpr int KQ4 = KLEN / 4;
    float4* hd = (float4*)hs;
    const float4* hp = (const float4*)hmat;
    for (int i = tid; i < 32 * KQ4; i += 256) {
      const int r = i / KQ4, off = i % KQ4;   // pow2 -> shifts
      hd[i] = hp[r * (HH / 4) + (k0 / 4) + off];
    }
  }
  __syncthreads();

  const int v0 = vb * 512 + tid;     // < 32000 always
  const int v1 = v0 + 256;
  const bool ok1 = (v1 < VV);        // vb==62: all false

  float acc0[32], acc1[32];
#pragma unroll
  for (int r = 0; r < 32; ++r) { acc0[r] = 0.0f; acc1[r] = 0.0f; }

  const float* w0p = Wt + (size_t)k0 * VV + v0;
  const float* w1p = ok1 ? (w0p + 256) : w0p;

  float wa[4], wb[4];
#pragma unroll
  for (int kk = 0; kk < 4; ++kk) {
    wa[kk] = w0p[(size_t)kk * VV];
    wb[kk] = w1p[(size_t)kk * VV];
  }

  for (int kg = 0; kg < KLEN; kg += 4) {
    float na[4], nb[4];
    if (kg + 4 < KLEN) {
      const float* n0 = w0p + (size_t)(kg + 4) * VV;
      const float* n1 = w1p + (size_t)(kg + 4) * VV;
#pragma unroll
      for (int kk = 0; kk < 4; ++kk) {
        na[kk] = n0[(size_t)kk * VV];
        nb[kk] = n1[(size_t)kk * VV];
      }
    }
#pragma unroll
    for (int r = 0; r < 32; ++r) {
      const float4 h4 = *(const float4*)&hs[r * KLEN + kg];  // broadcast
      acc0[r] = fmaf(h4.x, wa[0], acc0[r]);
      acc0[r] = fmaf(h4.y, wa[1], acc0[r]);
      acc0[r] = fmaf(h4.z, wa[2], acc0[r]);
      acc0[r] = fmaf(h4.w, wa[3], acc0[r]);
      acc1[r] = fmaf(h4.x, wb[0], acc1[r]);
      acc1[r] = fmaf(h4.y, wb[1], acc1[r]);
      acc1[r] = fmaf(h4.z, wb[2], acc1[r]);
      acc1[r] = fmaf(h4.w, wb[3], acc1[r]);
    }
    if (kg + 4 < KLEN) {
#pragma unroll
      for (int kk = 0; kk < 4; ++kk) { wa[kk] = na[kk]; wb[kk] = nb[kk]; }
    }
  }

  float* lp = lpart + (size_t)kc * BB * VV;
#pragma unroll
  for (int r = 0; r < 32; ++r) {
    lp[(size_t)r * VV + v0] = acc0[r];
    if (ok1) lp[(size_t)r * VV + v1] = acc1[r];
  }
}

// ---------------------------------------------------------------------------
// Combine: logits = sum_kc lpart + bias; per (row, 512-col chunk) emit
// max / argmax (lowest idx wins) / sum exp(l - max).
// Grid (63, 32 rows). Block 256 thr; thread = 2 adjacent cols.
// ---------------------------------------------------------------------------
__global__ __launch_bounds__(256) void k_combine(
    const float* __restrict__ lpart, const float* __restrict__ bout,
    float* __restrict__ pm, float* __restrict__ ps, int* __restrict__ pidx,
    const int nkc) {
  const int tid = threadIdx.x;
  const int vb = blockIdx.x;   // 0..62
  const int row = blockIdx.y;  // 0..31
  const int c0 = vb * 512 + tid * 2;
  const bool act = (c0 + 1 < VV);  // per-block: all-true or all-false pairs

  float l0 = 0.0f, l1 = 0.0f;
  if (act) {
    for (int kc = 0; kc < nkc; ++kc) {
      const float2 p = *(const float2*)(lpart + ((size_t)kc * BB + row) * VV + c0);
      l0 += p.x; l1 += p.y;
    }
    const float2 b2 = *(const float2*)(bout + c0);
    l0 += b2.x; l1 += b2.y;
  }
  float tm = -FLT_MAX; int ti = 0x7fffffff;
  if (act) {
    tm = l0; ti = c0;
    if (l1 > tm) { tm = l1; ti = c0 + 1; }
  }
#pragma unroll
  for (int off = 1; off < 64; off <<= 1) {
    const float om = __shfl_xor(tm, off);
    const int oi = __shfl_xor(ti, off);
    if (om > tm || (om == tm && oi < ti)) { tm = om; ti = oi; }
  }
  __shared__ float wm[4]; __shared__ int wi[4];
  __shared__ float bm_s; __shared__ int bi_s;
  __shared__ float wsum[4];
  const int wv = tid >> 6, lane = tid & 63;
  if (lane == 0) { wm[wv] = tm; wi[wv] = ti; }
  __syncthreads();
  if (tid == 0) {
    float m = wm[0]; int ii = wi[0];
#pragma unroll
    for (int w = 1; w < 4; ++w) {
      if (wm[w] > m || (wm[w] == m && wi[w] < ii)) { m = wm[w]; ii = wi[w]; }
    }
    bm_s = m; bi_s = ii;
  }
  __syncthreads();
  const float bm = bm_s;
  float sv = act ? (__expf(l0 - bm) + __expf(l1 - bm)) : 0.0f;
#pragma unroll
  for (int off = 1; off < 64; off <<= 1) sv += __shfl_xor(sv, off);
  if (lane == 0) wsum[wv] = sv;
  __syncthreads();
  if (tid == 0) {
    pm[row * PSTR + vb] = bm;
    ps[row * PSTR + vb] = wsum[0] + wsum[1] + wsum[2] + wsum[3];
    pidx[row * PSTR + vb] = bi_s;
  }
}

// ---------------------------------------------------------------------------
// GRU step with fused token-select prologue. Grid 128 = (rg 0..7 of 4 rows) x
// (jt 0..15 of 32 H-cols). Block 256 thr. Native-layout W_ih/W_hh reads.
// step==TSTEPS: select only.
// ---------------------------------------------------------------------------
__global__ __launch_bounds__(256) void k_gru(
    const int step,
    const float* __restrict__ emb,
    const float* __restrict__ W_ih,   // (1536, 256) native
    const float* __restrict__ W_hh,   // (1536, 512) native
    const float* __restrict__ b_ih, const float* __restrict__ b_hh,
    const float* __restrict__ hin, float* __restrict__ hout,
    const float* __restrict__ pm, const float* __restrict__ ps,
    const int* __restrict__ pidx,
    float* __restrict__ scores, int* __restrict__ tok_seq) {
  const int tid = threadIdx.x;
  const int rg = blockIdx.x >> 4;   // 0..7
  const int jt = blockIdx.x & 15;   // 0..15
  const int r0 = rg * 4, j0 = jt * 32;
  const int lane = tid & 63, wv = tid >> 6;  // wv 0..3

  __shared__ int toks[4];
  __shared__ float xs[4][EE];
  __shared__ float hsm[4][HH];
  __shared__ float gpart[24 * 272];

  // ---- select: reduce 63 chunk-partials for row r0+wv ----
  if (step == 0) {
    if (tid < 4) toks[tid] = 1;  // START
  } else {
    const int row = r0 + wv;
    const bool cv = (lane < NVCH);
    const float m = cv ? pm[row * PSTR + lane] : -FLT_MAX;
    const float s = cv ? ps[row * PSTR + lane] : 0.0f;
    const int ix = cv ? pidx[row * PSTR + lane] : 0x7fffffff;
    float gm = m; int gi = ix;
#pragma unroll
    for (int off = 1; off < 64; off <<= 1) {
      const float om = __shfl_xor(gm, off);
      const int oi = __shfl_xor(gi, off);
      if (om > gm || (om == gm && oi < gi)) { gm = om; gi = oi; }
    }
    float term = cv ? s * __expf(m - gm) : 0.0f;
#pragma unroll
    for (int off = 1; off < 64; off <<= 1) term += __shfl_xor(term, off);
    if (lane == 0) {
      toks[wv] = gi;
      if (jt == 0) {
        scores[row] -= logf(term);      // += max - logsumexp
        tok_seq[step * BB + row] = gi;  // seq column `step`
      }
    }
  }
  __syncthreads();
  if (step == TSTEPS) return;

  // ---- stage x = relu(emb[tok]) and h_prev ----
  for (int i = tid; i < 4 * EE; i += 256) {
    const int r = i >> 8, c = i & (EE - 1);
    const float e = emb[(size_t)toks[r] * EE + c];
    xs[r][c] = e > 0.0f ? e : 0.0f;
  }
  for (int i = tid; i < 4 * HH; i += 256) {
    const int r = i >> 9, c = i & (HH - 1);
    hsm[r][c] = hin[(r0 + r) * HH + c];
  }
  __syncthreads();

  const int jh = tid & 31, kq = tid >> 5;  // 32 cols x 8 k-slices
  const int j = j0 + jh;
  float ai[3][4], ah[3][4];
#pragma unroll
  for (int g = 0; g < 3; ++g)
#pragma unroll
    for (int r = 0; r < 4; ++r) { ai[g][r] = 0.0f; ah[g][r] = 0.0f; }

#pragma unroll 2
  for (int q = 0; q < 8; ++q) {
    const int k4 = kq * 32 + q * 4;
    float4 xr[4];
#pragma unroll
    for (int r = 0; r < 4; ++r) xr[r] = *(const float4*)&xs[r][k4];
#pragma unroll
    for (int g = 0; g < 3; ++g) {
      const float4 w = *(const float4*)&W_ih[(size_t)(g * HH + j) * EE + k4];
#pragma unroll
      for (int r = 0; r < 4; ++r) {
        ai[g][r] = fmaf(xr[r].x, w.x, ai[g][r]);
        ai[g][r] = fmaf(xr[r].y, w.y, ai[g][r]);
        ai[g][r] = fmaf(xr[r].z, w.z, ai[g][r]);
        ai[g][r] = fmaf(xr[r].w, w.w, ai[g][r]);
      }
    }
  }
#pragma unroll 2
  for (int q = 0; q < 16; ++q) {
    const int k4 = kq * 64 + q * 4;
    float4 hr[4];
#pragma unroll
    for (int r = 0; r < 4; ++r) hr[r] = *(const float4*)&hsm[r][k4];
#pragma unroll
    for (int g = 0; g < 3; ++g) {
      const float4 w = *(const float4*)&W_hh[(size_t)(g * HH + j) * HH + k4];
#pragma unroll
      for (int r = 0; r < 4; ++r) {
        ah[g][r] = fmaf(hr[r].x, w.x, ah[g][r]);
        ah[g][r] = fmaf(hr[r].y, w.y, ah[g][r]);
        ah[g][r] = fmaf(hr[r].z, w.z, ah[g][r]);
        ah[g][r] = fmaf(hr[r].w, w.w, ah[g][r]);
      }
    }
  }
  {
    const int base = kq * 34 + jh;
#pragma unroll
    for (int g = 0; g < 3; ++g)
#pragma unroll
      for (int r = 0; r < 4; ++r) {
        gpart[(g * 4 + r) * 272 + base] = ai[g][r];
        gpart[(12 + g * 4 + r) * 272 + base] = ah[g][r];
      }
  }
  __syncthreads();

  if (tid < 128) {
    const int r = tid >> 5, jh2 = tid & 31;
    const int j2 = j0 + jh2;
    float g6[6];
#pragma unroll
    for (int c = 0; c < 6; ++c) {
      const int cc = (c < 3) ? (c * 4 + r) : (12 + (c - 3) * 4 + r);
      float s = 0.0f;
#pragma unroll
      for (int q = 0; q < 8; ++q) s += gpart[cc * 272 + q * 34 + jh2];
      g6[c] = s;
    }
    const float ir = g6[0] + b_ih[j2];
    const float iz = g6[1] + b_ih[HH + j2];
    const float in_ = g6[2] + b_ih[2 * HH + j2];
    const float hr_ = g6[3] + b_hh[j2];
    const float hz = g6[4] + b_hh[HH + j2];
    const float hn = g6[5] + b_hh[2 * HH + j2];
    const float rr = 1.0f / (1.0f + expf(-(ir + hr_)));
    const float zz = 1.0f / (1.0f + expf(-(iz + hz)));
    const float nn = tanhf(in_ + rr * hn);
    hout[(r0 + r) * HH + j2] = (1.0f - zz) * nn + zz * hsm[r][j2];
  }
}

// ---------------------------------------------------------------------------
// Full-output writer: one-hot rows composed inline (no memset), h x3,
// scores x3. All stores float4, coalesced.
// ---------------------------------------------------------------------------
__global__ __launch_bounds__(256) void k_out(
    const int* __restrict__ tok_seq, const float* __restrict__ hfin,
    const float* __restrict__ scores, float* __restrict__ out) {
  const int blk = blockIdx.x, tid = threadIdx.x;
  if (blk < BB * (TSTEPS + 1)) {           // one (b,t) one-hot row
    const int b = blk / (TSTEPS + 1), t = blk % (TSTEPS + 1);
    const int tok = tok_seq[t * BB + b];
    const int tq = tok >> 2, tl = tok & 3;
    float4* op = (float4*)(out + (size_t)blk * VV);
    for (int i = tid; i < VV / 4; i += 256) {
      float4 z = {0.0f, 0.0f, 0.0f, 0.0f};
      if (i == tq) (&z.x)[tl] = 1.0f;
      op[i] = z;
    }
  } else if (blk < BB * (TSTEPS + 1) + 12) {  // h x3: 12288 float4
#pragma unroll
    for (int it = 0; it < 4; ++it) {
      const int idx = (blk - BB * (TSTEPS + 1)) * 1024 + it * 256 + tid;
      if (idx < H_ELEMS / 4) {
        const int fi = idx * 4;
        const int b = fi / (3 * HH);
        const int j0 = (fi % (3 * HH)) % HH;
        ((float4*)(out + DEC_ELEMS))[idx] =
            *(const float4*)(hfin + b * HH + j0);
      }
    }
  } else {                                   // scores x3: 96 floats
    if (tid < BB * 3) {
      out[(size_t)DEC_ELEMS + H_ELEMS + tid] = scores[tid / 3];
    }
  }
}

// ---------------------------------------------------------------------------
extern "C" void kernel_launch(void* const* d_in, const int* in_sizes, int n_in,
                              void* d_out, int out_size, void* d_ws, size_t ws_size,
                              hipStream_t stream) {
  const float* enc_h = (const float*)d_in[1];
  const float* emb   = (const float*)d_in[2];
  const float* W_ih  = (const float*)d_in[3];
  const float* W_hh  = (const float*)d_in[4];
  const float* b_ih  = (const float*)d_in[5];
  const float* b_hh  = (const float*)d_in[6];
  const float* W_out = (const float*)d_in[7];
  const float* b_out = (const float*)d_in[8];
  float* out = (float*)d_out;

  // workspace layout (floats)
  float* ws = (float*)d_ws;
  float* Wt_out  = ws;                       // 16,384,000
  float* hb0     = Wt_out + 16384000;        // 16,384
  float* hb1     = hb0 + BB * HH;            // 16,384
  float* pm      = hb1 + BB * HH;            // 32*64
  float* ps      = pm + BB * PSTR;           // 32*64
  float* scores  = ps + BB * PSTR;           // 32
  int*   pidx    = (int*)(scores + BB);      // 32*64
  int*   tok_seq = pidx + BB * PSTR;         // 33*32
  float* lpart   = (float*)(tok_seq + BB * (TSTEPS + 1));  // nkc*32*32000

  // fixed floats before lpart
  const size_t fixed = 16384000 + 2ull * BB * HH + 2ull * BB * PSTR + BB +
                       BB * PSTR + BB * (TSTEPS + 1);
  int nkc = 8;                               // prefer 2 waves/SIMD
  if (ws_size < (fixed + 8ull * BB * VV) * 4) nkc = 4;   // proven-fit fallback
  if (ws_size < (fixed + 4ull * BB * VV) * 4) nkc = 2;

  k_transpose_out<<<dim3(1000, 16), 256, 0, stream>>>(W_out, Wt_out);
  k_init<<<64, 256, 0, stream>>>(enc_h, hb0, scores, tok_seq);

  for (int t = 0; t < TSTEPS; ++t) {
    float* hin  = (t & 1) ? hb1 : hb0;
    float* hout = (t & 1) ? hb0 : hb1;
    k_gru<<<128, 256, 0, stream>>>(t, emb, W_ih, W_hh, b_ih, b_hh,
                                   hin, hout, pm, ps, pidx, scores, tok_seq);
    if (nkc == 8)
      k_gemv<64><<<dim3(63, 8), 256, 0, stream>>>(Wt_out, hout, lpart);
    else if (nkc == 4)
      k_gemv<128><<<dim3(63, 4), 256, 0, stream>>>(Wt_out, hout, lpart);
    else
      k_gemv<256><<<dim3(63, 2), 256, 0, stream>>>(Wt_out, hout, lpart);
    k_combine<<<dim3(63, BB), 256, 0, stream>>>(lpart, b_out, pm, ps, pidx, nkc);
  }
  // final selection: seq col 32 + last score term
  k_gru<<<128, 256, 0, stream>>>(TSTEPS, emb, W_ih, W_hh, b_ih, b_hh,
                                 hb0, hb1, pm, ps, pidx, scores, tok_seq);
  // final h lives in hb0 (t=31 odd: hout=hb0); full-output writer
  k_out<<<BB * (TSTEPS + 1) + 13, 256, 0, stream>>>(tok_seq, hb0, scores, out);
}